// Round 6
// baseline (144.088 us; speedup 1.0000x reference)
//
#include <hip/hip_runtime.h>
#include <hip/hip_bf16.h>
#include <math.h>

#define T_LEN 512
#define H_HEADS 8
#define DK 64
#define LR 128      // L_TABLES * R = 8 * 16
#define NTOT 32     // M*B*H

typedef __attribute__((ext_vector_type(8))) short bf16x8;   // MFMA A/B frag (8 bf16)
typedef __attribute__((ext_vector_type(4))) float f32x4;    // MFMA C/D frag

__device__ __forceinline__ float fast_tanh(float x) {
    float e = __expf(2.0f * x);
    return 1.0f - 2.0f / (1.0f + e);
}

__device__ __forceinline__ unsigned f2bf(float x) {
    union { float f; unsigned u; } v; v.f = x;
    unsigned r = v.u + 0x7FFF + ((v.u >> 16) & 1);   // RNE
    return r >> 16;
}

// Grid barrier: all 256 blocks are co-resident (1/CU by LDS), so spin is safe.
// Agent-scope release/acquire gives cross-XCD visibility of plain stores.
__device__ __forceinline__ void grid_barrier(unsigned* cnt, unsigned target) {
    __syncthreads();
    if (threadIdx.x == 0) {
        __hip_atomic_fetch_add(cnt, 1u, __ATOMIC_RELEASE, __HIP_MEMORY_SCOPE_AGENT);
        while (__hip_atomic_load(cnt, __ATOMIC_ACQUIRE, __HIP_MEMORY_SCOPE_AGENT) < target)
            __builtin_amdgcn_s_sleep(2);
    }
    __syncthreads();
}

// One persistent kernel: 256 blocks x 512 threads, 93.5 KB LDS (1 block/CU).
// Phase A: probs (projection GEMM + tanh + softmax) -> fp32 [n][lr][t]; V->bf16 [n][d][t]
// Phase B: per-(n,lr) causal cumsum; qw=pQ/(A+eps); bf16 pack [n][lr][t]
// Phase C: MFMA causal attention (R5 structure: 2 wave-groups x 4 m-band waves)
__global__ __launch_bounds__(512) void k_fused(
    const float* __restrict__ Khf, const float* __restrict__ Qhf,
    const float* __restrict__ Vhf,
    const float* __restrict__ planesT, const float* __restrict__ protosT,
    float* __restrict__ pKT, float* __restrict__ pQT,
    unsigned short* __restrict__ qwB, unsigned short* __restrict__ pKB,
    unsigned short* __restrict__ VBT,
    float* __restrict__ out, unsigned* __restrict__ counters)
{
    __shared__ __align__(16) unsigned char smraw[93568];

    const int tid = threadIdx.x;
    const int bx  = blockIdx.x;
    const int n   = bx >> 3;            // 0..31
    const int t0  = (bx & 7) * 64;      // phase A tile / phase C rt*64
    const int rt  = bx & 7;
    const int g   = n >> 3, h = n & 7;

    // ================= Phase A: probs + V pack =================
    {
        float* sm     = (float*)smraw;
        float* planes = sm;                   // [64][32]   2048
        float* protos = sm + 2048;            // [4][16]    64
        float* XT     = sm + 2112;            // [64][132]  8448
        float* xt     = sm + 10560;           // [128][33]  4224
        float* pbuf   = sm + 14784;           // [128][67]  8576

#pragma unroll
        for (int m = 0; m < 4; ++m) planes[m * 512 + tid] = planesT[m * 512 + tid];
        if (tid < 64) protos[tid] = protosT[tid];

#pragma unroll
        for (int m = 0; m < 4; ++m) {
            int fid = m * 512 + tid;                  // 2048 = 128 t2 x 16 c4
            int t2 = fid >> 4, c4 = fid & 15;
            const float* src = (t2 < 64 ? Khf : Qhf) +
                ((long)(g * T_LEN + t0 + (t2 & 63)) * H_HEADS + h) * DK + c4 * 4;
            float4 v = *(const float4*)src;
            XT[(c4 * 4 + 0) * 132 + t2] = v.x;
            XT[(c4 * 4 + 1) * 132 + t2] = v.y;
            XT[(c4 * 4 + 2) * 132 + t2] = v.z;
            XT[(c4 * 4 + 3) * 132 + t2] = v.w;
        }
        __syncthreads();

        // projection GEMM: [128 t2][32 j], K=64; 4x2 tile per thread
        {
            const int a4 = tid & 31;          // t2 quad
            const int b2 = tid >> 5;          // j pair (0..15)
            float pr[4][2] = {};
#pragma unroll 8
            for (int d = 0; d < 64; ++d) {
                float4 a = *(const float4*)(XT + d * 132 + a4 * 4);
                float2 b = *(const float2*)(planes + d * 32 + b2 * 2);
                float av[4] = {a.x, a.y, a.z, a.w};
#pragma unroll
                for (int ii = 0; ii < 4; ++ii) {
                    pr[ii][0] += av[ii] * b.x;
                    pr[ii][1] += av[ii] * b.y;
                }
            }
#pragma unroll
            for (int ii = 0; ii < 4; ++ii)
#pragma unroll
                for (int jj = 0; jj < 2; ++jj)
                    xt[(a4 * 4 + ii) * 33 + b2 * 2 + jj] = fast_tanh(pr[ii][jj]) * 0.125f;
        }
        __syncthreads();

        // per-table softmax over 16 corners (|logit| <= 0.5, no max-subtract)
        const int r = tid & 15, l = (tid >> 4) & 7, thi = tid >> 7;   // thi 0..3
        for (int side = 0; side < 2; ++side) {
            float p0 = protos[r], p1 = protos[16 + r], p2 = protos[32 + r], p3 = protos[48 + r];
#pragma unroll 4
            for (int w2 = 0; w2 < 16; ++w2) {
                int tl = w2 * 4 + thi;
                const float* x = xt + (side * 64 + tl) * 33 + l * 4;
                float logit = x[0] * p0 + x[1] * p1 + x[2] * p2 + x[3] * p3;
                float e = __expf(logit);
                float s = e;
                s += __shfl_xor(s, 1, 16);
                s += __shfl_xor(s, 2, 16);
                s += __shfl_xor(s, 4, 16);
                s += __shfl_xor(s, 8, 16);
                pbuf[(l * 16 + r) * 67 + tl] = e / s;
            }
            __syncthreads();
            float* dst = side ? pQT : pKT;
#pragma unroll 4
            for (int w2 = 0; w2 < 16; ++w2) {
                int idx = w2 * 512 + tid;
                int tl = idx & 63, lr = idx >> 6;
                dst[(long)(n * LR + lr) * T_LEN + t0 + tl] = pbuf[lr * 67 + tl];
            }
            __syncthreads();
        }

        // V pack: [t][d] fp32 -> VBT[n][d][t] bf16 via LDS transpose
        float* vb = XT;   // reuse (64 x 65)
#pragma unroll
        for (int it = 0; it < 2; ++it) {
            int fid = it * 512 + tid;                 // 1024 = 64 t x 16 c4
            int t = fid >> 4, c4 = fid & 15;
            float4 v = *(const float4*)(Vhf + ((size_t)(g * T_LEN + t0 + t) * H_HEADS + h) * DK + c4 * 4);
            vb[(c4 * 4 + 0) * 65 + t] = v.x;
            vb[(c4 * 4 + 1) * 65 + t] = v.y;
            vb[(c4 * 4 + 2) * 65 + t] = v.z;
            vb[(c4 * 4 + 3) * 65 + t] = v.w;
        }
        __syncthreads();
        {
            unsigned* dstv = (unsigned*)VBT + (size_t)n * 16384 + t0 / 2;
#pragma unroll
            for (int it = 0; it < 4; ++it) {
                int fid = it * 512 + tid;             // 2048 = 64 d x 32 t-pairs
                int d = fid >> 5, tp = (fid & 31) * 2;
                unsigned u0 = f2bf(vb[d * 65 + tp]);
                unsigned u1 = f2bf(vb[d * 65 + tp + 1]);
                dstv[d * 256 + tp / 2] = u0 | (u1 << 16);
            }
        }
    }

    grid_barrier(counters + 0, 256u);

    // ================= Phase B: cumsum + bf16 pack =================
    {
        const int wave = tid >> 6, lane = tid & 63;
#pragma unroll
        for (int rep = 0; rep < 2; ++rep) {
            int row = bx * 16 + wave * 2 + rep;       // 0..4095 = n*128+lr
            long base = (long)row * T_LEN + lane * 8;
            float4 ka = *(const float4*)(pKT + base);
            float4 kb = *(const float4*)(pKT + base + 4);
            float s[8];
            s[0] = ka.x;        s[1] = s[0] + ka.y; s[2] = s[1] + ka.z; s[3] = s[2] + ka.w;
            s[4] = s[3] + kb.x; s[5] = s[4] + kb.y; s[6] = s[5] + kb.z; s[7] = s[6] + kb.w;
            float tot = s[7];
#pragma unroll
            for (int off = 1; off < 64; off <<= 1) {
                float v = __shfl_up(tot, off, 64);
                if (lane >= off) tot += v;
            }
            float excl = tot - s[7];
            float4 qa = *(const float4*)(pQT + base);
            float4 qb = *(const float4*)(pQT + base + 4);
            float o[8];
            o[0] = qa.x / (excl + s[0] + 1e-6f);
            o[1] = qa.y / (excl + s[1] + 1e-6f);
            o[2] = qa.z / (excl + s[2] + 1e-6f);
            o[3] = qa.w / (excl + s[3] + 1e-6f);
            o[4] = qb.x / (excl + s[4] + 1e-6f);
            o[5] = qb.y / (excl + s[5] + 1e-6f);
            o[6] = qb.z / (excl + s[6] + 1e-6f);
            o[7] = qb.w / (excl + s[7] + 1e-6f);

            uint4 qv, kv;
            qv.x = f2bf(o[0]) | (f2bf(o[1]) << 16);
            qv.y = f2bf(o[2]) | (f2bf(o[3]) << 16);
            qv.z = f2bf(o[4]) | (f2bf(o[5]) << 16);
            qv.w = f2bf(o[6]) | (f2bf(o[7]) << 16);
            kv.x = f2bf(ka.x) | (f2bf(ka.y) << 16);
            kv.y = f2bf(ka.z) | (f2bf(ka.w) << 16);
            kv.z = f2bf(kb.x) | (f2bf(kb.y) << 16);
            kv.w = f2bf(kb.z) | (f2bf(kb.w) << 16);
            *(uint4*)((unsigned*)qwB + (size_t)row * 256 + lane * 4) = qv;
            *(uint4*)((unsigned*)pKB + (size_t)row * 256 + lane * 4) = kv;
        }
    }

    grid_barrier(counters + 16, 256u);

    // ================= Phase C: MFMA causal attention =================
    {
        short* sm2  = (short*)smraw;
        short* Qsh  = sm2;                 // [64][136]; aliased as Obuf f32 later
        short* Ksh0 = sm2 + 8704;          // [64][136]
        short* Ksh1 = sm2 + 17408;
        short* Vsh0 = sm2 + 26112;         // [64][72]
        short* Vsh1 = sm2 + 30720;
        short* Ssh0 = sm2 + 35328;         // [64][72]
        short* Ssh1 = sm2 + 39936;
        float* Obuf = (float*)sm2;         // [64][68]

        const int wave = tid >> 6, wg = wave >> 2, w = wave & 3;
        const int lane = tid & 63, m16 = lane & 15, q = lane >> 4;
        const int gtid = tid & 255;

        short* Ksh = wg ? Ksh1 : Ksh0;
        short* Vsh = wg ? Vsh1 : Vsh0;
        short* Ssh = wg ? Ssh1 : Ssh0;

        const unsigned short* kq = qwB + (size_t)n * 65536;   // [lr][t]
        const unsigned short* kk = pKB + (size_t)n * 65536;   // [lr][t]
        const unsigned short* kv = VBT + (size_t)n * 32768;   // [d][t]

        // stage Q: transpose [lr][t-span] -> Qsh[t_local][lr]
#pragma unroll
        for (int it = 0; it < 2; ++it) {
            int fid = it * 512 + tid;                 // 1024 = 128 lr x 8 seg
            int lr = fid >> 3, seg = fid & 7;
            uint4 u = *(const uint4*)(kq + (size_t)lr * 512 + rt * 64 + seg * 8);
            unsigned uu[4] = {u.x, u.y, u.z, u.w};
#pragma unroll
            for (int p = 0; p < 4; ++p) {
                Qsh[(seg * 8 + 2 * p) * 136 + lr]     = (short)(uu[p] & 0xFFFFu);
                Qsh[(seg * 8 + 2 * p + 1) * 136 + lr] = (short)(uu[p] >> 16);
            }
        }
        __syncthreads();
        bf16x8 qa[4];
#pragma unroll
        for (int st = 0; st < 4; ++st)
            qa[st] = *(const bf16x8*)(Qsh + (w * 16 + m16) * 136 + st * 32 + q * 8);

        uint4 pk[4], pv[2];
        auto pref = [&](int c) {
#pragma unroll
            for (int it = 0; it < 4; ++it) {
                int fid = it * 256 + gtid;
                pk[it] = *(const uint4*)(kk + (size_t)(fid >> 3) * 512 + c * 64 + (fid & 7) * 8);
            }
#pragma unroll
            for (int it = 0; it < 2; ++it) {
                int fid = it * 256 + gtid;
                pv[it] = *(const uint4*)(kv + (size_t)(fid >> 3) * 512 + c * 64 + (fid & 7) * 8);
            }
        };

        f32x4 o[4];
        o[0] = o[1] = o[2] = o[3] = (f32x4){0.f, 0.f, 0.f, 0.f};

        if (wg <= rt) pref(wg);
        const int rounds = (rt >> 1) + 1;
        for (int rr0 = 0; rr0 < rounds; ++rr0) {
            const int c = 2 * rr0 + wg;
            const bool act = (c <= rt);
            __syncthreads();
            if (act) {
#pragma unroll
                for (int it = 0; it < 4; ++it) {
                    int fid = it * 256 + gtid;
                    int lr = fid >> 3, seg = fid & 7;
                    unsigned uu[4] = {pk[it].x, pk[it].y, pk[it].z, pk[it].w};
#pragma unroll
                    for (int p = 0; p < 4; ++p) {
                        Ksh[(seg * 8 + 2 * p) * 136 + lr]     = (short)(uu[p] & 0xFFFFu);
                        Ksh[(seg * 8 + 2 * p + 1) * 136 + lr] = (short)(uu[p] >> 16);
                    }
                }
                *(uint4*)(Vsh + (gtid >> 3) * 72 + (gtid & 7) * 8) = pv[0];
                *(uint4*)(Vsh + ((gtid + 256) >> 3) * 72 + (gtid & 7) * 8) = pv[1];
            }
            __syncthreads();
            if (c + 2 <= rt) pref(c + 2);
            if (act) {
                f32x4 s[4];
                s[0] = s[1] = s[2] = s[3] = (f32x4){0.f, 0.f, 0.f, 0.f};
#pragma unroll
                for (int st = 0; st < 4; ++st)
#pragma unroll
                    for (int nb = 0; nb < 4; ++nb) {
                        bf16x8 b = *(const bf16x8*)(Ksh + (nb * 16 + m16) * 136 + st * 32 + q * 8);
                        s[nb] = __builtin_amdgcn_mfma_f32_16x16x32_bf16(qa[st], b, s[nb], 0, 0, 0);
                    }
                if (c == rt) {                         // causal: keep j <= i
#pragma unroll
                    for (int nb = 0; nb < 4; ++nb)
#pragma unroll
                        for (int p = 0; p < 4; ++p)
                            if (nb * 16 + m16 > w * 16 + q * 4 + p) s[nb][p] = 0.f;
                }
#pragma unroll
                for (int nb = 0; nb < 4; ++nb)
#pragma unroll
                    for (int p = 0; p < 4; ++p) {
                        union { float f; unsigned u; } cv; cv.f = s[nb][p];
                        Ssh[(w * 16 + q * 4 + p) * 72 + nb * 16 + m16] =
                            (short)((cv.u + 0x8000u) >> 16);
                    }
#pragma unroll
                for (int st = 0; st < 2; ++st) {
                    bf16x8 a = *(const bf16x8*)(Ssh + (w * 16 + m16) * 72 + st * 32 + q * 8);
#pragma unroll
                    for (int nb = 0; nb < 4; ++nb) {
                        bf16x8 b = *(const bf16x8*)(Vsh + (nb * 16 + m16) * 72 + st * 32 + q * 8);
                        o[nb] = __builtin_amdgcn_mfma_f32_16x16x32_bf16(a, b, o[nb], 0, 0, 0);
                    }
                }
            }
        }

        __syncthreads();                               // compute done; Qsh -> Obuf
        if (wg == 1) {
#pragma unroll
            for (int nb = 0; nb < 4; ++nb)
#pragma unroll
                for (int p = 0; p < 4; ++p)
                    Obuf[(w * 16 + q * 4 + p) * 68 + nb * 16 + m16] = o[nb][p];
        }
        __syncthreads();
        if (wg == 0) {
            float* ob = out + ((size_t)(g * T_LEN + rt * 64 + w * 16 + q * 4) * H_HEADS + h) * DK;
#pragma unroll
            for (int p = 0; p < 4; ++p)
#pragma unroll
                for (int nb = 0; nb < 4; ++nb)
                    ob[p * (H_HEADS * DK) + nb * 16 + m16] =
                        o[nb][p] + Obuf[(w * 16 + q * 4 + p) * 68 + nb * 16 + m16];
        }
    }
}

extern "C" void kernel_launch(void* const* d_in, const int* in_sizes, int n_in,
                              void* d_out, int out_size, void* d_ws, size_t ws_size,
                              hipStream_t stream) {
    const float* Khf     = (const float*)d_in[0];
    const float* Vhf     = (const float*)d_in[1];
    const float* Qhf     = (const float*)d_in[2];
    const float* planesT = (const float*)d_in[3];
    const float* protosT = (const float*)d_in[4];
    float* outp = (float*)d_out;

    unsigned* counters = (unsigned*)d_ws;               // [0,1024) zeroed below
    const size_t NE = (size_t)NTOT * LR * T_LEN;        // 2,097,152
    float* pKT = (float*)((char*)d_ws + 1024);          // fp32 [n][lr][t]
    float* pQT = pKT + NE;                              // fp32 [n][lr][t]
    unsigned short* qwB = (unsigned short*)(pQT + NE);  // bf16 [n][lr][t]
    unsigned short* pKB = qwB + NE;                     // bf16 [n][lr][t]
    unsigned short* VBT = pKB + NE;                     // bf16 [n][d][t]

    hipMemsetAsync(d_ws, 0, 1024, stream);              // zero barrier counters
    k_fused<<<dim3(256), dim3(512), 0, stream>>>(
        Khf, Qhf, Vhf, planesT, protosT, pKT, pQT, qwB, pKB, VBT, outp, counters);
}

// Round 7
// 124.293 us; speedup vs baseline: 1.1593x; 1.1593x over previous
//
#include <hip/hip_runtime.h>
#include <hip/hip_bf16.h>
#include <math.h>

#define T_LEN 512
#define H_HEADS 8
#define DK 64
#define LR 128      // L_TABLES * R = 8 * 16
#define NTOT 32     // M*B*H

typedef __attribute__((ext_vector_type(8))) short bf16x8;   // MFMA A/B frag (8 bf16)
typedef __attribute__((ext_vector_type(4))) float f32x4;    // MFMA C/D frag

__device__ __forceinline__ float fast_tanh(float x) {
    float e = __expf(2.0f * x);
    return 1.0f - 2.0f / (1.0f + e);
}

__device__ __forceinline__ unsigned f2bf(float x) {
    union { float f; unsigned u; } v; v.f = x;
    unsigned r = v.u + 0x7FFF + ((v.u >> 16) & 1);   // RNE
    return r >> 16;
}

// K1: per (n, 64-t tile): projections -> tanh -> per-table softmax.
// Outputs: pKT/pQT fp32 [n][lr][t], pKB bf16 [n][lr][t], VBT bf16 [n][d][t].
__global__ __launch_bounds__(256) void k_probs(
    const float* __restrict__ Khf, const float* __restrict__ Qhf,
    const float* __restrict__ Vhf,
    const float* __restrict__ planesT, const float* __restrict__ protosT,
    float* __restrict__ pKT, float* __restrict__ pQT,
    unsigned short* __restrict__ pKB, unsigned short* __restrict__ VBT)
{
    __shared__ float sm[23360];
    float* planes = sm;                   // [64][32]    2048
    float* protos = sm + 2048;            // [4][16]     64
    float* XT     = sm + 2112;            // [64][132]   8448
    float* xt     = sm + 10560;           // [128][33]   4224
    float* pbuf   = sm + 14784;           // [128][67]   8576

    const int bx = blockIdx.x;
    const int n  = bx >> 3;
    const int t0 = (bx & 7) * 64;
    const int g  = n >> 3, h = n & 7;
    const int tid = threadIdx.x;

#pragma unroll
    for (int m = 0; m < 8; ++m) planes[m * 256 + tid] = planesT[m * 256 + tid];
    if (tid < 64) protos[tid] = protosT[tid];

#pragma unroll
    for (int m = 0; m < 8; ++m) {
        int fid = m * 256 + tid;
        int t2 = fid >> 4, c4 = fid & 15;
        const float* src = (t2 < 64 ? Khf : Qhf) +
            ((long)(g * T_LEN + t0 + (t2 & 63)) * H_HEADS + h) * DK + c4 * 4;
        float4 v = *(const float4*)src;
        XT[(c4 * 4 + 0) * 132 + t2] = v.x;
        XT[(c4 * 4 + 1) * 132 + t2] = v.y;
        XT[(c4 * 4 + 2) * 132 + t2] = v.z;
        XT[(c4 * 4 + 3) * 132 + t2] = v.w;
    }
    __syncthreads();

    {
        const int a4 = tid & 31;
        const int b4 = tid >> 5;
        float pr[4][4] = {};
#pragma unroll 8
        for (int d = 0; d < 64; ++d) {
            float4 a = *(const float4*)(XT + d * 132 + a4 * 4);
            float4 b = *(const float4*)(planes + d * 32 + b4 * 4);
            float av[4] = {a.x, a.y, a.z, a.w};
            float bv[4] = {b.x, b.y, b.z, b.w};
#pragma unroll
            for (int ii = 0; ii < 4; ++ii)
#pragma unroll
                for (int jj = 0; jj < 4; ++jj) pr[ii][jj] += av[ii] * bv[jj];
        }
#pragma unroll
        for (int ii = 0; ii < 4; ++ii)
#pragma unroll
            for (int jj = 0; jj < 4; ++jj)
                xt[(a4 * 4 + ii) * 33 + b4 * 4 + jj] = fast_tanh(pr[ii][jj]) * 0.125f;
    }
    __syncthreads();

    const int r = tid & 15, l = (tid >> 4) & 7, thi = tid >> 7;
    for (int side = 0; side < 2; ++side) {
        float p0 = protos[r], p1 = protos[16 + r], p2 = protos[32 + r], p3 = protos[48 + r];
#pragma unroll 4
        for (int w = 0; w < 32; ++w) {
            int tl = w * 2 + thi;
            const float* x = xt + (side * 64 + tl) * 33 + l * 4;
            float logit = x[0] * p0 + x[1] * p1 + x[2] * p2 + x[3] * p3;
            float e = __expf(logit);
            float s = e;
            s += __shfl_xor(s, 1, 16);
            s += __shfl_xor(s, 2, 16);
            s += __shfl_xor(s, 4, 16);
            s += __shfl_xor(s, 8, 16);
            pbuf[(l * 16 + r) * 67 + tl] = e / s;
        }
        __syncthreads();
        float* dst = side ? pQT : pKT;
#pragma unroll 4
        for (int w = 0; w < 32; ++w) {
            int idx = w * 256 + tid;
            int tl = idx & 63, lr = idx >> 6;
            dst[(long)(n * LR + lr) * T_LEN + t0 + tl] = pbuf[lr * 67 + tl];
        }
        if (side == 0) {
            // pK bf16 pack: pbuf [128][t] -> pKB [n][lr][t] (dword = 2 t)
            unsigned* dk = (unsigned*)pKB;
#pragma unroll
            for (int it = 0; it < 16; ++it) {
                int fid = it * 256 + tid;             // 4096 = 128 lr x 32 t-pairs
                int lr = fid >> 5, tp = (fid & 31) * 2;
                unsigned u0 = f2bf(pbuf[lr * 67 + tp]);
                unsigned u1 = f2bf(pbuf[lr * 67 + tp + 1]);
                dk[(size_t)(n * LR + lr) * 256 + t0 / 2 + (tp >> 1)] = u0 | (u1 << 16);
            }
        }
        __syncthreads();
    }

    // V pack: [t][d] fp32 -> VBT[n][d][t] bf16 via LDS transpose
    float* vb = XT;   // reuse (64 x 65)
#pragma unroll
    for (int it = 0; it < 4; ++it) {
        int fid = it * 256 + tid;
        int t = fid >> 4, c4 = fid & 15;
        float4 v = *(const float4*)(Vhf + ((size_t)(g * T_LEN + t0 + t) * H_HEADS + h) * DK + c4 * 4);
        vb[(c4 * 4 + 0) * 65 + t] = v.x;
        vb[(c4 * 4 + 1) * 65 + t] = v.y;
        vb[(c4 * 4 + 2) * 65 + t] = v.z;
        vb[(c4 * 4 + 3) * 65 + t] = v.w;
    }
    __syncthreads();
    {
        unsigned* dstv = (unsigned*)VBT + (size_t)n * 16384 + t0 / 2;
#pragma unroll
        for (int it = 0; it < 8; ++it) {
            int fid = it * 256 + tid;
            int d = fid >> 5, tp = (fid & 31) * 2;
            unsigned u0 = f2bf(vb[d * 65 + tp]);
            unsigned u1 = f2bf(vb[d * 65 + tp + 1]);
            dstv[d * 256 + (tp >> 1)] = u0 | (u1 << 16);
        }
    }
}

// K2: MFMA causal attention, 1024 thr = 4 wave-groups x 4 m-band waves.
// In-kernel A-prefix + qw (replaces k_cumsum). Chunks c == wg (mod 4).
// XOR-swizzled LDS layout for K/Q: phys col-group = (col>>3) ^ (row>>3).
__global__ __launch_bounds__(1024) void k_attn(
    const float* __restrict__ pKT, const float* __restrict__ pQT,
    const unsigned short* __restrict__ pKB, const unsigned short* __restrict__ VBT,
    float* __restrict__ out)
{
    __shared__ __align__(16) short sm[71680];      // 143,360 B
    // Ksh[wg] = sm + wg*8704   (64 rows x 136, swizzled)
    // Vsh[wg] = sm + 34816 + wg*4608   (64 x 72)
    // Ssh[wg] = sm + 53248 + wg*4608   (64 x 72)
    // Qsh aliases sm[0..8704) (dead before round 0); Obuf f32 aliases sm after loop

    const int n = blockIdx.x >> 3, rt = blockIdx.x & 7;
    const int g = n >> 3, h = n & 7;
    const int tid = threadIdx.x;
    const int wave = tid >> 6, wg = wave >> 2, w = wave & 3;
    const int lane = tid & 63, m16 = lane & 15, q = lane >> 4;
    const int gtid = tid & 255;

    short* Ksh = sm + wg * 8704;
    short* Vsh = sm + 34816 + wg * 4608;
    short* Ssh = sm + 53248 + wg * 4608;
    short* Qsh = sm;

    // ---- A-prefix + qw -> Qsh (bf16, swizzled) ----
    {
        const int s8 = lane & 7;
        const int lr = wave * 8 + (lane >> 3);     // 16 waves x 8 = 128
        const float* kr = pKT + ((size_t)(n * LR + lr)) * T_LEN;
        const float* qr = pQT + ((size_t)(n * LR + lr)) * T_LEN;
        float bsum = 0.f;
        for (int j = 0; j < rt; ++j) {             // base = sum over [0, rt*64)
            float4 a = *(const float4*)(kr + j * 64 + s8 * 8);
            float4 b = *(const float4*)(kr + j * 64 + s8 * 8 + 4);
            bsum += (a.x + a.y + a.z + a.w) + (b.x + b.y + b.z + b.w);
        }
        bsum += __shfl_xor(bsum, 1, 8);
        bsum += __shfl_xor(bsum, 2, 8);
        bsum += __shfl_xor(bsum, 4, 8);
        float4 ka = *(const float4*)(kr + rt * 64 + s8 * 8);
        float4 kb = *(const float4*)(kr + rt * 64 + s8 * 8 + 4);
        float s[8];
        s[0] = ka.x;        s[1] = s[0] + ka.y; s[2] = s[1] + ka.z; s[3] = s[2] + ka.w;
        s[4] = s[3] + kb.x; s[5] = s[4] + kb.y; s[6] = s[5] + kb.z; s[7] = s[6] + kb.w;
        float tot = s[7];
#pragma unroll
        for (int off = 1; off < 8; off <<= 1) {    // segmented scan (width 8)
            float v = __shfl_up(tot, off, 8);
            if (s8 >= off) tot += v;
        }
        float base = bsum + tot - s[7];            // exclusive-in-tile + global base
        float4 qa4 = *(const float4*)(qr + rt * 64 + s8 * 8);
        float4 qb4 = *(const float4*)(qr + rt * 64 + s8 * 8 + 4);
        float qq[8] = {qa4.x, qa4.y, qa4.z, qa4.w, qb4.x, qb4.y, qb4.z, qb4.w};
        const int qbase = ((wave ^ s8) << 3) + (lane & 7 & 7) * 0 + (lr & 7);  // lr>>3 == wave
#pragma unroll
        for (int i = 0; i < 8; ++i) {
            float a = base + s[i];
            Qsh[(s8 * 8 + i) * 136 + qbase] = (short)f2bf(qq[i] / (a + 1e-6f));
        }
    }
    __syncthreads();

    bf16x8 qa[4];
    {
        const int row = w * 16 + m16, rk = row >> 3;
#pragma unroll
        for (int st = 0; st < 4; ++st)
            qa[st] = *(const bf16x8*)(Qsh + row * 136 + (((st * 4 + q) ^ rk) << 3));
    }

    const unsigned short* kk = pKB + (size_t)n * 65536;   // [lr][t]
    const unsigned short* kv = VBT + (size_t)n * 32768;   // [d][t]
    uint4 pk[4], pv[2];
    auto pref = [&](int c) {
#pragma unroll
        for (int it = 0; it < 4; ++it) {
            int fid = it * 256 + gtid;
            pk[it] = *(const uint4*)(kk + (size_t)(fid >> 3) * 512 + c * 64 + (fid & 7) * 8);
        }
#pragma unroll
        for (int it = 0; it < 2; ++it) {
            int fid = it * 256 + gtid;
            pv[it] = *(const uint4*)(kv + (size_t)(fid >> 3) * 512 + c * 64 + (fid & 7) * 8);
        }
    };

    f32x4 o[4];
    o[0] = o[1] = o[2] = o[3] = (f32x4){0.f, 0.f, 0.f, 0.f};

    if (wg <= rt) pref(wg);
    const int rounds = (rt >> 2) + 1;
    for (int r0 = 0; r0 < rounds; ++r0) {
        const int c = r0 * 4 + wg;
        const bool act = (c <= rt);
        __syncthreads();                           // prior round reads done (also Q stage)
        if (act) {
            // K: swizzled scatter-transpose [lr][t'] regs -> Ksh[j][lr]
#pragma unroll
            for (int it = 0; it < 4; ++it) {
                int fid = it * 256 + gtid;
                int lr = fid >> 3, seg = fid & 7;
                int kbase = (((lr >> 3) ^ seg) << 3) + (lr & 7);  // row>>3 == seg for all 8 rows
                unsigned uu[4] = {pk[it].x, pk[it].y, pk[it].z, pk[it].w};
#pragma unroll
                for (int p = 0; p < 4; ++p) {
                    Ksh[(seg * 8 + 2 * p) * 136 + kbase]     = (short)(uu[p] & 0xFFFFu);
                    Ksh[(seg * 8 + 2 * p + 1) * 136 + kbase] = (short)(uu[p] >> 16);
                }
            }
            *(uint4*)(Vsh + (gtid >> 3) * 72 + (gtid & 7) * 8) = pv[0];
            *(uint4*)(Vsh + ((gtid + 256) >> 3) * 72 + (gtid & 7) * 8) = pv[1];
        }
        __syncthreads();
        if (c + 4 <= rt) pref(c + 4);
        if (act) {
            f32x4 s[4];
            s[0] = s[1] = s[2] = s[3] = (f32x4){0.f, 0.f, 0.f, 0.f};
#pragma unroll
            for (int st = 0; st < 4; ++st)
#pragma unroll
                for (int nb = 0; nb < 4; ++nb) {
                    int row = nb * 16 + m16;
                    bf16x8 b = *(const bf16x8*)(Ksh + row * 136 + (((st * 4 + q) ^ (row >> 3)) << 3));
                    s[nb] = __builtin_amdgcn_mfma_f32_16x16x32_bf16(qa[st], b, s[nb], 0, 0, 0);
                }
            if (c == rt) {                         // causal: keep j <= i
#pragma unroll
                for (int nb = 0; nb < 4; ++nb)
#pragma unroll
                    for (int p = 0; p < 4; ++p)
                        if (nb * 16 + m16 > w * 16 + q * 4 + p) s[nb][p] = 0.f;
            }
#pragma unroll
            for (int nb = 0; nb < 4; ++nb)
#pragma unroll
                for (int p = 0; p < 4; ++p) {
                    union { float f; unsigned u; } cv; cv.f = s[nb][p];
                    Ssh[(w * 16 + q * 4 + p) * 72 + nb * 16 + m16] =
                        (short)((cv.u + 0x8000u) >> 16);
                }
#pragma unroll
            for (int st = 0; st < 2; ++st) {
                bf16x8 a = *(const bf16x8*)(Ssh + (w * 16 + m16) * 72 + st * 32 + q * 8);
#pragma unroll
                for (int nb = 0; nb < 4; ++nb) {
                    bf16x8 b = *(const bf16x8*)(Vsh + (nb * 16 + m16) * 72 + st * 32 + q * 8);
                    o[nb] = __builtin_amdgcn_mfma_f32_16x16x32_bf16(a, b, o[nb], 0, 0, 0);
                }
            }
        }
    }

    // combine 4 wave-group partials via LDS (K/Q regions dead)
    __syncthreads();
    float* Obuf = (float*)sm;                      // 3 x [64][68] f32
    if (wg) {
        float* ob = Obuf + (wg - 1) * 4352;
#pragma unroll
        for (int nb = 0; nb < 4; ++nb)
#pragma unroll
            for (int p = 0; p < 4; ++p)
                ob[(w * 16 + q * 4 + p) * 68 + nb * 16 + m16] = o[nb][p];
    }
    __syncthreads();
    if (wg == 0) {
        float* dst = out + ((size_t)(g * T_LEN + rt * 64 + w * 16 + q * 4) * H_HEADS + h) * DK;
#pragma unroll
        for (int p = 0; p < 4; ++p)
#pragma unroll
            for (int nb = 0; nb < 4; ++nb) {
                int idx = (w * 16 + q * 4 + p) * 68 + nb * 16 + m16;
                dst[p * (H_HEADS * DK) + nb * 16 + m16] =
                    o[nb][p] + Obuf[idx] + Obuf[4352 + idx] + Obuf[8704 + idx];
            }
    }
}

extern "C" void kernel_launch(void* const* d_in, const int* in_sizes, int n_in,
                              void* d_out, int out_size, void* d_ws, size_t ws_size,
                              hipStream_t stream) {
    const float* Khf     = (const float*)d_in[0];
    const float* Vhf     = (const float*)d_in[1];
    const float* Qhf     = (const float*)d_in[2];
    const float* planesT = (const float*)d_in[3];
    const float* protosT = (const float*)d_in[4];
    float* outp = (float*)d_out;

    const size_t NE = (size_t)NTOT * LR * T_LEN;        // 2,097,152
    float* pKT = (float*)d_ws;                          // fp32 [n][lr][t]
    float* pQT = pKT + NE;                              // fp32 [n][lr][t]
    unsigned short* pKB = (unsigned short*)(pQT + NE);  // bf16 [n][lr][t]
    unsigned short* VBT = pKB + NE;                     // bf16 [n][d][t]

    k_probs<<<dim3(256), dim3(256), 0, stream>>>(
        Khf, Qhf, Vhf, planesT, protosT, pKT, pQT, pKB, VBT);
    k_attn<<<dim3(256), dim3(1024), 0, stream>>>(pKT, pQT, pKB, VBT, outp);
}

// Round 8
// 111.767 us; speedup vs baseline: 1.2892x; 1.1121x over previous
//
#include <hip/hip_runtime.h>
#include <hip/hip_bf16.h>
#include <math.h>

#define T_LEN 512
#define H_HEADS 8
#define DK 64
#define LR 128      // L_TABLES * R = 8 * 16
#define NTOT 32     // M*B*H

typedef __attribute__((ext_vector_type(8))) short bf16x8;   // MFMA A/B frag (8 bf16)
typedef __attribute__((ext_vector_type(4))) float f32x4;    // MFMA C/D frag

__device__ __forceinline__ float fast_tanh(float x) {
    float e = __expf(2.0f * x);
    return 1.0f - 2.0f / (1.0f + e);
}

__device__ __forceinline__ unsigned f2bf(float x) {
    union { float f; unsigned u; } v; v.f = x;
    unsigned r = v.u + 0x7FFF + ((v.u >> 16) & 1);   // RNE
    return r >> 16;
}

__device__ __forceinline__ float bflo(unsigned u) {   // low bf16 of dword -> f32
    union { unsigned u; float f; } v; v.u = u << 16; return v.f;
}
__device__ __forceinline__ float bfhi(unsigned u) {   // high bf16 of dword -> f32
    union { unsigned u; float f; } v; v.u = u & 0xFFFF0000u; return v.f;
}

// K1: per (n, 32-t tile): projections -> tanh -> per-table softmax.
// Outputs (all bf16 except Spart): pKB/pQB [n][lr][t], VBT [n][d][t],
// Spart fp32 [n][tile32][lr] (per-tile pK sums for k_attn's A-prefix).
// 512 blocks x 256 thr, ~34 KB LDS -> 2+ blocks/CU.
__global__ __launch_bounds__(256) void k_probs(
    const float* __restrict__ Khf, const float* __restrict__ Qhf,
    const float* __restrict__ Vhf,
    const float* __restrict__ planesT, const float* __restrict__ protosT,
    unsigned short* __restrict__ pKB, unsigned short* __restrict__ pQB,
    unsigned short* __restrict__ VBT, float* __restrict__ Spart)
{
    __shared__ float sm[8576];            // 34.3 KB
    float* planes = sm;                   // [64][32]   2048
    float* protos = sm + 2048;            // [4][16]    64
    float* XT     = sm + 2112;            // [64][68]   4352 (d-major, t2 0..63)
    float* xt     = sm + 6464;            // [64][33]   2112 (tanh'd proj)
    float* pbuf   = sm + 2112;            // [128][33]  4224 (aliases XT, post-GEMM)
    float* vb     = sm + 6464;            // [64][33]   aliases xt (post-softmax)

    const int bx = blockIdx.x;
    const int n  = bx >> 4;               // 0..31
    const int tile = bx & 15;             // 0..15
    const int t0 = tile * 32;
    const int g  = n >> 3, h = n & 7;
    const int tid = threadIdx.x;

#pragma unroll
    for (int m = 0; m < 8; ++m) planes[m * 256 + tid] = planesT[m * 256 + tid];
    if (tid < 64) protos[tid] = protosT[tid];

    // stage + transpose: rows t2 0..31 = K[t0..t0+31], 32..63 = Q[t0..t0+31]
#pragma unroll
    for (int m = 0; m < 4; ++m) {
        int fid = m * 256 + tid;                  // 1024 = 64 t2 x 16 c4
        int t2 = fid >> 4, c4 = fid & 15;
        const float* src = (t2 < 32 ? Khf : Qhf) +
            ((long)(g * T_LEN + t0 + (t2 & 31)) * H_HEADS + h) * DK + c4 * 4;
        float4 v = *(const float4*)src;
        XT[(c4 * 4 + 0) * 68 + t2] = v.x;
        XT[(c4 * 4 + 1) * 68 + t2] = v.y;
        XT[(c4 * 4 + 2) * 68 + t2] = v.z;
        XT[(c4 * 4 + 3) * 68 + t2] = v.w;
    }
    __syncthreads();

    // projection GEMM: [64 t2][32 j], K=64; 4x2 per thread
    {
        const int a4 = tid & 15;          // t2 quad
        const int b2 = tid >> 4;          // j pair (0..15)
        float pr[4][2] = {};
#pragma unroll 8
        for (int d = 0; d < 64; ++d) {
            float4 a = *(const float4*)(XT + d * 68 + a4 * 4);
            float2 b = *(const float2*)(planes + d * 32 + b2 * 2);
            float av[4] = {a.x, a.y, a.z, a.w};
#pragma unroll
            for (int ii = 0; ii < 4; ++ii) {
                pr[ii][0] += av[ii] * b.x;
                pr[ii][1] += av[ii] * b.y;
            }
        }
        __syncthreads();                  // XT reads done; pbuf may alias it
#pragma unroll
        for (int ii = 0; ii < 4; ++ii)
#pragma unroll
            for (int jj = 0; jj < 2; ++jj)
                xt[(a4 * 4 + ii) * 33 + b2 * 2 + jj] = fast_tanh(pr[ii][jj]) * 0.125f;
    }
    __syncthreads();

    // per-table softmax over 16 corners (|logit| <= 0.5, no max-subtract)
    const int r = tid & 15, l = (tid >> 4) & 7, thi = tid >> 7;   // thi 0/1
    for (int side = 0; side < 2; ++side) {
        float p0 = protos[r], p1 = protos[16 + r], p2 = protos[32 + r], p3 = protos[48 + r];
#pragma unroll 4
        for (int w = 0; w < 16; ++w) {
            int tl = w * 2 + thi;                 // 0..31
            const float* x = xt + (side * 32 + tl) * 33 + l * 4;
            float logit = x[0] * p0 + x[1] * p1 + x[2] * p2 + x[3] * p3;
            float e = __expf(logit);
            float s = e;
            s += __shfl_xor(s, 1, 16);
            s += __shfl_xor(s, 2, 16);
            s += __shfl_xor(s, 4, 16);
            s += __shfl_xor(s, 8, 16);
            pbuf[(l * 16 + r) * 33 + tl] = e / s;
        }
        __syncthreads();
        // bf16 pack: pbuf [128 lr][32 t] -> (pKB|pQB)[n][lr][t0..t0+32)
        unsigned* dst = (unsigned*)(side ? pQB : pKB);
#pragma unroll
        for (int it = 0; it < 8; ++it) {
            int fid = it * 256 + tid;             // 2048 = 128 lr x 16 dwords
            int lr = fid >> 4, tp2 = fid & 15;
            unsigned u0 = f2bf(pbuf[lr * 33 + tp2 * 2]);
            unsigned u1 = f2bf(pbuf[lr * 33 + tp2 * 2 + 1]);
            dst[(size_t)(n * LR + lr) * 256 + tile * 16 + tp2] = u0 | (u1 << 16);
        }
        if (side == 0 && tid < 128) {             // per-tile pK row sums (fp32)
            float s = 0.f;
            const float* row = pbuf + tid * 33;
#pragma unroll 8
            for (int t = 0; t < 32; ++t) s += row[t];
            Spart[((size_t)n * 16 + tile) * 128 + tid] = s;
        }
        __syncthreads();
    }

    // V pack: [t][d] fp32 -> VBT[n][d][t] bf16 via LDS transpose (vb aliases xt)
#pragma unroll
    for (int it = 0; it < 2; ++it) {
        int fid = it * 256 + tid;                 // 512 = 32 t x 16 c4
        int t = fid >> 4, c4 = fid & 15;
        float4 v = *(const float4*)(Vhf + ((size_t)(g * T_LEN + t0 + t) * H_HEADS + h) * DK + c4 * 4);
        vb[(c4 * 4 + 0) * 33 + t] = v.x;
        vb[(c4 * 4 + 1) * 33 + t] = v.y;
        vb[(c4 * 4 + 2) * 33 + t] = v.z;
        vb[(c4 * 4 + 3) * 33 + t] = v.w;
    }
    __syncthreads();
    {
        unsigned* dstv = (unsigned*)VBT + (size_t)n * 16384;
#pragma unroll
        for (int it = 0; it < 4; ++it) {
            int fid = it * 256 + tid;             // 1024 = 64 d x 16 dwords
            int d = fid >> 4, tp2 = fid & 15;
            unsigned u0 = f2bf(vb[d * 33 + tp2 * 2]);
            unsigned u1 = f2bf(vb[d * 33 + tp2 * 2 + 1]);
            dstv[d * 256 + tile * 16 + tp2] = u0 | (u1 << 16);
        }
    }
}

// K2: MFMA causal attention, 1024 thr = 4 wave-groups x 4 m-band waves.
// A-prefix from Spart + bf16 in-tile scan; qw from bf16 pQB. Chunks c == wg
// (mod 4). XOR-swizzled K/Q LDS: phys col-group = (col>>3) ^ (row>>3).
__global__ __launch_bounds__(1024) void k_attn(
    const unsigned short* __restrict__ pKB, const unsigned short* __restrict__ pQB,
    const unsigned short* __restrict__ VBT, const float* __restrict__ Spart,
    float* __restrict__ out)
{
    __shared__ __align__(16) short sm[71680];      // 143,360 B
    const int n = blockIdx.x >> 3, rt = blockIdx.x & 7;
    const int g = n >> 3, h = n & 7;
    const int tid = threadIdx.x;
    const int wave = tid >> 6, wg = wave >> 2, w = wave & 3;
    const int lane = tid & 63, m16 = lane & 15, q = lane >> 4;
    const int gtid = tid & 255;

    short* Ksh = sm + wg * 8704;                   // [64][136] swizzled
    short* Vsh = sm + 34816 + wg * 4608;           // [64][72]
    short* Ssh = sm + 53248 + wg * 4608;           // [64][72]
    short* Qsh = sm;                               // aliases Ksh[0] pre-loop

    // ---- A-prefix + qw -> Qsh (bf16, swizzled) ----
    {
        const int s8 = lane & 7;
        const int lr = wave * 8 + (lane >> 3);     // 16 waves x 8 = 128
        float bsum = 0.f;
        for (int j = 0; j < 2 * rt; ++j)           // 32-t tile sums below rt*64
            bsum += Spart[((size_t)n * 16 + j) * 128 + lr];
        uint4 ku = *(const uint4*)(pKB + ((size_t)n * LR + lr) * 512 + rt * 64 + s8 * 8);
        unsigned kuu[4] = {ku.x, ku.y, ku.z, ku.w};
        float s[8];
        s[0] = bflo(kuu[0]);        s[1] = s[0] + bfhi(kuu[0]);
        s[2] = s[1] + bflo(kuu[1]); s[3] = s[2] + bfhi(kuu[1]);
        s[4] = s[3] + bflo(kuu[2]); s[5] = s[4] + bfhi(kuu[2]);
        s[6] = s[5] + bflo(kuu[3]); s[7] = s[6] + bfhi(kuu[3]);
        float tot = s[7];
#pragma unroll
        for (int off = 1; off < 8; off <<= 1) {    // segmented scan (width 8)
            float v = __shfl_up(tot, off, 8);
            if (s8 >= off) tot += v;
        }
        float base = bsum + tot - s[7];            // exclusive prefix before lane's span
        uint4 qu = *(const uint4*)(pQB + ((size_t)n * LR + lr) * 512 + rt * 64 + s8 * 8);
        unsigned quu[4] = {qu.x, qu.y, qu.z, qu.w};
        float qf[8] = {bflo(quu[0]), bfhi(quu[0]), bflo(quu[1]), bfhi(quu[1]),
                       bflo(quu[2]), bfhi(quu[2]), bflo(quu[3]), bfhi(quu[3])};
        const int qbase = ((wave ^ s8) << 3) + (lr & 7);   // lr>>3 == wave
#pragma unroll
        for (int i = 0; i < 8; ++i)
            Qsh[(s8 * 8 + i) * 136 + qbase] = (short)f2bf(qf[i] / (base + s[i] + 1e-6f));
    }
    __syncthreads();

    bf16x8 qa[4];
    {
        const int row = w * 16 + m16, rk = row >> 3;
#pragma unroll
        for (int st = 0; st < 4; ++st)
            qa[st] = *(const bf16x8*)(Qsh + row * 136 + (((st * 4 + q) ^ rk) << 3));
    }

    const unsigned short* kk = pKB + (size_t)n * 65536;   // [lr][t]
    const unsigned short* kv = VBT + (size_t)n * 32768;   // [d][t]
    uint4 pk[4], pv[2];
    auto pref = [&](int c) {
#pragma unroll
        for (int it = 0; it < 4; ++it) {
            int fid = it * 256 + gtid;
            pk[it] = *(const uint4*)(kk + (size_t)(fid >> 3) * 512 + c * 64 + (fid & 7) * 8);
        }
#pragma unroll
        for (int it = 0; it < 2; ++it) {
            int fid = it * 256 + gtid;
            pv[it] = *(const uint4*)(kv + (size_t)(fid >> 3) * 512 + c * 64 + (fid & 7) * 8);
        }
    };

    f32x4 o[4];
    o[0] = o[1] = o[2] = o[3] = (f32x4){0.f, 0.f, 0.f, 0.f};

    if (wg <= rt) pref(wg);
    const int rounds = (rt >> 2) + 1;
    for (int r0 = 0; r0 < rounds; ++r0) {
        const int c = r0 * 4 + wg;
        const bool act = (c <= rt);
        __syncthreads();                           // prior round reads done (also Q stage)
        if (act) {
            // K: swizzled scatter-transpose [lr][t'] regs -> Ksh[j][lr]
#pragma unroll
            for (int it = 0; it < 4; ++it) {
                int fid = it * 256 + gtid;
                int lr = fid >> 3, seg = fid & 7;
                int kbase = (((lr >> 3) ^ seg) << 3) + (lr & 7);  // row>>3 == seg
                unsigned uu[4] = {pk[it].x, pk[it].y, pk[it].z, pk[it].w};
#pragma unroll
                for (int p = 0; p < 4; ++p) {
                    Ksh[(seg * 8 + 2 * p) * 136 + kbase]     = (short)(uu[p] & 0xFFFFu);
                    Ksh[(seg * 8 + 2 * p + 1) * 136 + kbase] = (short)(uu[p] >> 16);
                }
            }
            *(uint4*)(Vsh + (gtid >> 3) * 72 + (gtid & 7) * 8) = pv[0];
            *(uint4*)(Vsh + ((gtid + 256) >> 3) * 72 + (gtid & 7) * 8) = pv[1];
        }
        __syncthreads();
        if (c + 4 <= rt) pref(c + 4);
        if (act) {
            f32x4 s[4];
            s[0] = s[1] = s[2] = s[3] = (f32x4){0.f, 0.f, 0.f, 0.f};
#pragma unroll
            for (int st = 0; st < 4; ++st)
#pragma unroll
                for (int nb = 0; nb < 4; ++nb) {
                    int row = nb * 16 + m16;
                    bf16x8 b = *(const bf16x8*)(Ksh + row * 136 + (((st * 4 + q) ^ (row >> 3)) << 3));
                    s[nb] = __builtin_amdgcn_mfma_f32_16x16x32_bf16(qa[st], b, s[nb], 0, 0, 0);
                }
            if (c == rt) {                         // causal: keep j <= i
#pragma unroll
                for (int nb = 0; nb < 4; ++nb)
#pragma unroll
                    for (int p = 0; p < 4; ++p)
                        if (nb * 16 + m16 > w * 16 + q * 4 + p) s[nb][p] = 0.f;
            }
#pragma unroll
            for (int nb = 0; nb < 4; ++nb)
#pragma unroll
                for (int p = 0; p < 4; ++p) {
                    union { float f; unsigned u; } cv; cv.f = s[nb][p];
                    Ssh[(w * 16 + q * 4 + p) * 72 + nb * 16 + m16] =
                        (short)((cv.u + 0x8000u) >> 16);
                }
#pragma unroll
            for (int st = 0; st < 2; ++st) {
                bf16x8 a = *(const bf16x8*)(Ssh + (w * 16 + m16) * 72 + st * 32 + q * 8);
#pragma unroll
                for (int nb = 0; nb < 4; ++nb) {
                    bf16x8 b = *(const bf16x8*)(Vsh + (nb * 16 + m16) * 72 + st * 32 + q * 8);
                    o[nb] = __builtin_amdgcn_mfma_f32_16x16x32_bf16(a, b, o[nb], 0, 0, 0);
                }
            }
        }
    }

    // combine 4 wave-group partials via LDS (K/Q regions dead)
    __syncthreads();
    float* Obuf = (float*)sm;                      // 3 x [64][68] f32
    if (wg) {
        float* ob = Obuf + (wg - 1) * 4352;
#pragma unroll
        for (int nb = 0; nb < 4; ++nb)
#pragma unroll
            for (int p = 0; p < 4; ++p)
                ob[(w * 16 + q * 4 + p) * 68 + nb * 16 + m16] = o[nb][p];
    }
    __syncthreads();
    if (wg == 0) {
        float* dst = out + ((size_t)(g * T_LEN + rt * 64 + w * 16 + q * 4) * H_HEADS + h) * DK;
#pragma unroll
        for (int p = 0; p < 4; ++p)
#pragma unroll
            for (int nb = 0; nb < 4; ++nb) {
                int idx = (w * 16 + q * 4 + p) * 68 + nb * 16 + m16;
                dst[p * (H_HEADS * DK) + nb * 16 + m16] =
                    o[nb][p] + Obuf[idx] + Obuf[4352 + idx] + Obuf[8704 + idx];
            }
    }
}

extern "C" void kernel_launch(void* const* d_in, const int* in_sizes, int n_in,
                              void* d_out, int out_size, void* d_ws, size_t ws_size,
                              hipStream_t stream) {
    const float* Khf     = (const float*)d_in[0];
    const float* Vhf     = (const float*)d_in[1];
    const float* Qhf     = (const float*)d_in[2];
    const float* planesT = (const float*)d_in[3];
    const float* protosT = (const float*)d_in[4];
    float* outp = (float*)d_out;

    const size_t NE = (size_t)NTOT * LR * T_LEN;        // 2,097,152
    unsigned short* pKB = (unsigned short*)d_ws;        // bf16 [n][lr][t]
    unsigned short* pQB = pKB + NE;                     // bf16 [n][lr][t]
    unsigned short* VBT = pQB + NE;                     // bf16 [n][d][t]
    float* Spart = (float*)(VBT + (size_t)NTOT * DK * T_LEN);  // fp32 [n][16][128]

    k_probs<<<dim3(512), dim3(256), 0, stream>>>(
        Khf, Qhf, Vhf, planesT, protosT, pKB, pQB, VBT, Spart);
    k_attn<<<dim3(256), dim3(1024), 0, stream>>>(pKB, pQB, VBT, Spart, outp);
}

// Round 9
// 109.082 us; speedup vs baseline: 1.3209x; 1.0246x over previous
//
#include <hip/hip_runtime.h>
#include <hip/hip_bf16.h>
#include <math.h>

#define T_LEN 512
#define H_HEADS 8
#define DK 64
#define LR 128      // L_TABLES * R = 8 * 16
#define NTOT 32     // M*B*H

typedef __attribute__((ext_vector_type(8))) short bf16x8;   // MFMA A/B frag (8 bf16)
typedef __attribute__((ext_vector_type(4))) float f32x4;    // MFMA C/D frag

__device__ __forceinline__ float fast_tanh(float x) {
    float e = __expf(2.0f * x);
    return 1.0f - 2.0f / (1.0f + e);
}

__device__ __forceinline__ unsigned f2bf(float x) {
    union { float f; unsigned u; } v; v.f = x;
    unsigned r = v.u + 0x7FFF + ((v.u >> 16) & 1);   // RNE
    return r >> 16;
}

__device__ __forceinline__ float bflo(unsigned u) {
    union { unsigned u; float f; } v; v.u = u << 16; return v.f;
}
__device__ __forceinline__ float bfhi(unsigned u) {
    union { unsigned u; float f; } v; v.u = u & 0xFFFF0000u; return v.f;
}

// K1: per (n, 32-t tile): projections -> tanh -> per-table softmax.
// Outputs: pKB [n][lr][t] (for A-prefix scan), pKt [n][t][lr] (MFMA B-operand
// layout, staged straight into LDS by k_attn), pQB [n][lr][t], VBT [n][d][t],
// Spart fp32 [n][tile32][lr].
__global__ __launch_bounds__(256) void k_probs(
    const float* __restrict__ Khf, const float* __restrict__ Qhf,
    const float* __restrict__ Vhf,
    const float* __restrict__ planesT, const float* __restrict__ protosT,
    unsigned short* __restrict__ pKB, unsigned short* __restrict__ pKt,
    unsigned short* __restrict__ pQB, unsigned short* __restrict__ VBT,
    float* __restrict__ Spart)
{
    __shared__ float sm[8576];            // 34.3 KB
    float* planes = sm;                   // [64][32]   2048
    float* protos = sm + 2048;            // [4][16]    64
    float* XT     = sm + 2112;            // [64][68]   4352 (d-major, t2 0..63)
    float* xt     = sm + 6464;            // [64][33]   2112 (tanh'd proj)
    float* pbuf   = sm + 2112;            // [128][33]  4224 (aliases XT, post-GEMM)
    float* vb     = sm + 6464;            // [64][33]   aliases xt (post-softmax)

    const int bx = blockIdx.x;
    const int n  = bx >> 4;               // 0..31
    const int tile = bx & 15;             // 0..15
    const int t0 = tile * 32;
    const int g  = n >> 3, h = n & 7;
    const int tid = threadIdx.x;

#pragma unroll
    for (int m = 0; m < 8; ++m) planes[m * 256 + tid] = planesT[m * 256 + tid];
    if (tid < 64) protos[tid] = protosT[tid];

    // stage + transpose: rows t2 0..31 = K[t0..t0+31], 32..63 = Q[t0..t0+31]
#pragma unroll
    for (int m = 0; m < 4; ++m) {
        int fid = m * 256 + tid;                  // 1024 = 64 t2 x 16 c4
        int t2 = fid >> 4, c4 = fid & 15;
        const float* src = (t2 < 32 ? Khf : Qhf) +
            ((long)(g * T_LEN + t0 + (t2 & 31)) * H_HEADS + h) * DK + c4 * 4;
        float4 v = *(const float4*)src;
        XT[(c4 * 4 + 0) * 68 + t2] = v.x;
        XT[(c4 * 4 + 1) * 68 + t2] = v.y;
        XT[(c4 * 4 + 2) * 68 + t2] = v.z;
        XT[(c4 * 4 + 3) * 68 + t2] = v.w;
    }
    __syncthreads();

    // projection GEMM: [64 t2][32 j], K=64; 4x2 per thread
    {
        const int a4 = tid & 15;          // t2 quad
        const int b2 = tid >> 4;          // j pair (0..15)
        float pr[4][2] = {};
#pragma unroll 8
        for (int d = 0; d < 64; ++d) {
            float4 a = *(const float4*)(XT + d * 68 + a4 * 4);
            float2 b = *(const float2*)(planes + d * 32 + b2 * 2);
            float av[4] = {a.x, a.y, a.z, a.w};
#pragma unroll
            for (int ii = 0; ii < 4; ++ii) {
                pr[ii][0] += av[ii] * b.x;
                pr[ii][1] += av[ii] * b.y;
            }
        }
        __syncthreads();                  // XT reads done; pbuf may alias it
#pragma unroll
        for (int ii = 0; ii < 4; ++ii)
#pragma unroll
            for (int jj = 0; jj < 2; ++jj)
                xt[(a4 * 4 + ii) * 33 + b2 * 2 + jj] = fast_tanh(pr[ii][jj]) * 0.125f;
    }
    __syncthreads();

    // per-table softmax over 16 corners (|logit| <= 0.5, no max-subtract)
    const int r = tid & 15, l = (tid >> 4) & 7, thi = tid >> 7;   // thi 0/1
    for (int side = 0; side < 2; ++side) {
        float p0 = protos[r], p1 = protos[16 + r], p2 = protos[32 + r], p3 = protos[48 + r];
#pragma unroll 4
        for (int w = 0; w < 16; ++w) {
            int tl = w * 2 + thi;                 // 0..31
            const float* x = xt + (side * 32 + tl) * 33 + l * 4;
            float logit = x[0] * p0 + x[1] * p1 + x[2] * p2 + x[3] * p3;
            float e = __expf(logit);
            float s = e;
            s += __shfl_xor(s, 1, 16);
            s += __shfl_xor(s, 2, 16);
            s += __shfl_xor(s, 4, 16);
            s += __shfl_xor(s, 8, 16);
            pbuf[(l * 16 + r) * 33 + tl] = e / s;
        }
        __syncthreads();
        // bf16 pack: pbuf [128 lr][32 t] -> (pKB|pQB)[n][lr][t0..t0+32)
        unsigned* dst = (unsigned*)(side ? pQB : pKB);
#pragma unroll
        for (int it = 0; it < 8; ++it) {
            int fid = it * 256 + tid;             // 2048 = 128 lr x 16 dwords
            int lr = fid >> 4, tp2 = fid & 15;
            unsigned u0 = f2bf(pbuf[lr * 33 + tp2 * 2]);
            unsigned u1 = f2bf(pbuf[lr * 33 + tp2 * 2 + 1]);
            dst[(size_t)(n * LR + lr) * 256 + tile * 16 + tp2] = u0 | (u1 << 16);
        }
        if (side == 0) {
            // transposed pack: pbuf [lr][t] -> pKt[n][t][lr] (coalesced dwords;
            // LDS reads at dword-stride 66 per lane -> conflict-light)
            unsigned* dt = (unsigned*)pKt + (size_t)n * 32768 + t0 * 64;
#pragma unroll
            for (int it = 0; it < 8; ++it) {
                int fid = it * 256 + tid;         // 2048 = 32 t x 64 lr-pairs
                int t = fid >> 6, lrp = fid & 63;
                unsigned u0 = f2bf(pbuf[(2 * lrp) * 33 + t]);
                unsigned u1 = f2bf(pbuf[(2 * lrp + 1) * 33 + t]);
                dt[t * 64 + lrp] = u0 | (u1 << 16);
            }
            if (tid < 128) {                      // per-tile pK row sums (fp32)
                float s = 0.f;
                const float* row = pbuf + tid * 33;
#pragma unroll 8
                for (int t = 0; t < 32; ++t) s += row[t];
                Spart[((size_t)n * 16 + tile) * 128 + tid] = s;
            }
        }
        __syncthreads();
    }

    // V pack: [t][d] fp32 -> VBT[n][d][t] bf16 via LDS transpose (vb aliases xt)
#pragma unroll
    for (int it = 0; it < 2; ++it) {
        int fid = it * 256 + tid;                 // 512 = 32 t x 16 c4
        int t = fid >> 4, c4 = fid & 15;
        float4 v = *(const float4*)(Vhf + ((size_t)(g * T_LEN + t0 + t) * H_HEADS + h) * DK + c4 * 4);
        vb[(c4 * 4 + 0) * 33 + t] = v.x;
        vb[(c4 * 4 + 1) * 33 + t] = v.y;
        vb[(c4 * 4 + 2) * 33 + t] = v.z;
        vb[(c4 * 4 + 3) * 33 + t] = v.w;
    }
    __syncthreads();
    {
        unsigned* dstv = (unsigned*)VBT + (size_t)n * 16384;
#pragma unroll
        for (int it = 0; it < 4; ++it) {
            int fid = it * 256 + tid;             // 1024 = 64 d x 16 dwords
            int d = fid >> 4, tp2 = fid & 15;
            unsigned u0 = f2bf(vb[d * 33 + tp2 * 2]);
            unsigned u1 = f2bf(vb[d * 33 + tp2 * 2 + 1]);
            dstv[d * 256 + tile * 16 + tp2] = u0 | (u1 << 16);
        }
    }
}

// K2: MFMA causal attention, 1024 thr = 4 wave-groups x 4 m-band waves.
// A-prefix from Spart + bf16 in-tile scan; qw from bf16 pQB. Chunks c == wg
// (mod 4). Ksh staged DIRECTLY from pKt[n][t][lr] via b128 (no per-round
// transpose). Q path keeps its one-time XOR-swizzled transpose.
__global__ __launch_bounds__(1024) void k_attn(
    const unsigned short* __restrict__ pKB, const unsigned short* __restrict__ pKt,
    const unsigned short* __restrict__ pQB, const unsigned short* __restrict__ VBT,
    const float* __restrict__ Spart, float* __restrict__ out)
{
    __shared__ __align__(16) short sm[71680];      // 143,360 B
    const int n = blockIdx.x >> 3, rt = blockIdx.x & 7;
    const int g = n >> 3, h = n & 7;
    const int tid = threadIdx.x;
    const int wave = tid >> 6, wg = wave >> 2, w = wave & 3;
    const int lane = tid & 63, m16 = lane & 15, q = lane >> 4;
    const int gtid = tid & 255;

    short* Ksh = sm + wg * 8704;                   // [64][136] plain padded
    short* Vsh = sm + 34816 + wg * 4608;           // [64][72]
    short* Ssh = sm + 53248 + wg * 4608;           // [64][72]
    short* Qsh = sm;                               // aliases Ksh[0] pre-loop (XOR-swizzled)

    // ---- A-prefix + qw -> Qsh (bf16, swizzled) ----
    {
        const int s8 = lane & 7;
        const int lr = wave * 8 + (lane >> 3);     // 16 waves x 8 = 128
        float bsum = 0.f;
        for (int j = 0; j < 2 * rt; ++j)           // 32-t tile sums below rt*64
            bsum += Spart[((size_t)n * 16 + j) * 128 + lr];
        uint4 ku = *(const uint4*)(pKB + ((size_t)n * LR + lr) * 512 + rt * 64 + s8 * 8);
        unsigned kuu[4] = {ku.x, ku.y, ku.z, ku.w};
        float s[8];
        s[0] = bflo(kuu[0]);        s[1] = s[0] + bfhi(kuu[0]);
        s[2] = s[1] + bflo(kuu[1]); s[3] = s[2] + bfhi(kuu[1]);
        s[4] = s[3] + bflo(kuu[2]); s[5] = s[4] + bfhi(kuu[2]);
        s[6] = s[5] + bflo(kuu[3]); s[7] = s[6] + bfhi(kuu[3]);
        float tot = s[7];
#pragma unroll
        for (int off = 1; off < 8; off <<= 1) {    // segmented scan (width 8)
            float v = __shfl_up(tot, off, 8);
            if (s8 >= off) tot += v;
        }
        float base = bsum + tot - s[7];            // exclusive prefix before lane's span
        uint4 qu = *(const uint4*)(pQB + ((size_t)n * LR + lr) * 512 + rt * 64 + s8 * 8);
        unsigned quu[4] = {qu.x, qu.y, qu.z, qu.w};
        float qf[8] = {bflo(quu[0]), bfhi(quu[0]), bflo(quu[1]), bfhi(quu[1]),
                       bflo(quu[2]), bfhi(quu[2]), bflo(quu[3]), bfhi(quu[3])};
        const int qbase = ((wave ^ s8) << 3) + (lr & 7);   // lr>>3 == wave
#pragma unroll
        for (int i = 0; i < 8; ++i)
            Qsh[(s8 * 8 + i) * 136 + qbase] = (short)f2bf(qf[i] / (base + s[i] + 1e-6f));
    }
    __syncthreads();

    bf16x8 qa[4];
    {
        const int row = w * 16 + m16, rk = row >> 3;
#pragma unroll
        for (int st = 0; st < 4; ++st)
            qa[st] = *(const bf16x8*)(Qsh + row * 136 + (((st * 4 + q) ^ rk) << 3));
    }

    const unsigned short* kt = pKt + (size_t)n * 65536;   // [t][lr]
    const unsigned short* kv = VBT + (size_t)n * 32768;   // [d][t]
    uint4 pk[4], pv[2];
    auto pref = [&](int c) {
#pragma unroll
        for (int it = 0; it < 4; ++it) {           // 1024 uint4 = 64 rows x 16 segs
            int fid = it * 256 + gtid;
            pk[it] = *(const uint4*)(kt + (size_t)(c * 64 + (fid >> 4)) * 128 + (fid & 15) * 8);
        }
#pragma unroll
        for (int it = 0; it < 2; ++it) {
            int fid = it * 256 + gtid;
            pv[it] = *(const uint4*)(kv + (size_t)(fid >> 3) * 512 + c * 64 + (fid & 7) * 8);
        }
    };

    f32x4 o[4];
    o[0] = o[1] = o[2] = o[3] = (f32x4){0.f, 0.f, 0.f, 0.f};

    if (wg <= rt) pref(wg);
    const int rounds = (rt >> 2) + 1;
    for (int r0 = 0; r0 < rounds; ++r0) {
        const int c = r0 * 4 + wg;
        const bool act = (c <= rt);
        __syncthreads();                           // prior round reads done (also Q stage)
        if (act) {
            // K: direct b128 rows into padded Ksh (banks balanced, no swizzle)
#pragma unroll
            for (int it = 0; it < 4; ++it) {
                int fid = it * 256 + gtid;
                *(uint4*)(Ksh + (fid >> 4) * 136 + (fid & 15) * 8) = pk[it];
            }
            *(uint4*)(Vsh + (gtid >> 3) * 72 + (gtid & 7) * 8) = pv[0];
            *(uint4*)(Vsh + ((gtid + 256) >> 3) * 72 + (gtid & 7) * 8) = pv[1];
        }
        __syncthreads();
        if (c + 4 <= rt) pref(c + 4);
        if (act) {
            f32x4 s[4];
            s[0] = s[1] = s[2] = s[3] = (f32x4){0.f, 0.f, 0.f, 0.f};
#pragma unroll
            for (int st = 0; st < 4; ++st)
#pragma unroll
                for (int nb = 0; nb < 4; ++nb) {
                    bf16x8 b = *(const bf16x8*)(Ksh + (nb * 16 + m16) * 136 + st * 32 + q * 8);
                    s[nb] = __builtin_amdgcn_mfma_f32_16x16x32_bf16(qa[st], b, s[nb], 0, 0, 0);
                }
            if (c == rt) {                         // causal: keep j <= i
#pragma unroll
                for (int nb = 0; nb < 4; ++nb)
#pragma unroll
                    for (int p = 0; p < 4; ++p)
                        if (nb * 16 + m16 > w * 16 + q * 4 + p) s[nb][p] = 0.f;
            }
#pragma unroll
            for (int nb = 0; nb < 4; ++nb)
#pragma unroll
                for (int p = 0; p < 4; ++p) {
                    union { float f; unsigned u; } cv; cv.f = s[nb][p];
                    Ssh[(w * 16 + q * 4 + p) * 72 + nb * 16 + m16] =
                        (short)((cv.u + 0x8000u) >> 16);
                }
#pragma unroll
            for (int st = 0; st < 2; ++st) {
                bf16x8 a = *(const bf16x8*)(Ssh + (w * 16 + m16) * 72 + st * 32 + q * 8);
#pragma unroll
                for (int nb = 0; nb < 4; ++nb) {
                    bf16x8 b = *(const bf16x8*)(Vsh + (nb * 16 + m16) * 72 + st * 32 + q * 8);
                    o[nb] = __builtin_amdgcn_mfma_f32_16x16x32_bf16(a, b, o[nb], 0, 0, 0);
                }
            }
        }
    }

    // combine 4 wave-group partials via LDS (K/Q regions dead)
    __syncthreads();
    float* Obuf = (float*)sm;                      // 3 x [64][68] f32
    if (wg) {
        float* ob = Obuf + (wg - 1) * 4352;
#pragma unroll
        for (int nb = 0; nb < 4; ++nb)
#pragma unroll
            for (int p = 0; p < 4; ++p)
                ob[(w * 16 + q * 4 + p) * 68 + nb * 16 + m16] = o[nb][p];
    }
    __syncthreads();
    if (wg == 0) {
        float* dst = out + ((size_t)(g * T_LEN + rt * 64 + w * 16 + q * 4) * H_HEADS + h) * DK;
#pragma unroll
        for (int p = 0; p < 4; ++p)
#pragma unroll
            for (int nb = 0; nb < 4; ++nb) {
                int idx = (w * 16 + q * 4 + p) * 68 + nb * 16 + m16;
                dst[p * (H_HEADS * DK) + nb * 16 + m16] =
                    o[nb][p] + Obuf[idx] + Obuf[4352 + idx] + Obuf[8704 + idx];
            }
    }
}

extern "C" void kernel_launch(void* const* d_in, const int* in_sizes, int n_in,
                              void* d_out, int out_size, void* d_ws, size_t ws_size,
                              hipStream_t stream) {
    const float* Khf     = (const float*)d_in[0];
    const float* Vhf     = (const float*)d_in[1];
    const float* Qhf     = (const float*)d_in[2];
    const float* planesT = (const float*)d_in[3];
    const float* protosT = (const float*)d_in[4];
    float* outp = (float*)d_out;

    const size_t NE = (size_t)NTOT * LR * T_LEN;        // 2,097,152
    unsigned short* pKB = (unsigned short*)d_ws;        // bf16 [n][lr][t]
    unsigned short* pKt = pKB + NE;                     // bf16 [n][t][lr]
    unsigned short* pQB = pKt + NE;                     // bf16 [n][lr][t]
    unsigned short* VBT = pQB + NE;                     // bf16 [n][d][t]
    float* Spart = (float*)(VBT + (size_t)NTOT * DK * T_LEN);  // fp32 [n][16][128]

    k_probs<<<dim3(512), dim3(256), 0, stream>>>(
        Khf, Qhf, Vhf, planesT, protosT, pKB, pKt, pQB, VBT, Spart);
    k_attn<<<dim3(256), dim3(1024), 0, stream>>>(pKB, pKt, pQB, VBT, Spart, outp);
}

// Round 10
// 107.930 us; speedup vs baseline: 1.3350x; 1.0107x over previous
//
#include <hip/hip_runtime.h>
#include <hip/hip_bf16.h>
#include <math.h>

#define T_LEN 512
#define H_HEADS 8
#define DK 64
#define LR 128      // L_TABLES * R = 8 * 16
#define NTOT 32     // M*B*H

typedef __attribute__((ext_vector_type(8))) short bf16x8;   // MFMA A/B frag (8 bf16)
typedef __attribute__((ext_vector_type(4))) float f32x4;    // MFMA C/D frag

__device__ __forceinline__ float fast_tanh(float x) {
    float e = __expf(2.0f * x);
    return 1.0f - 2.0f / (1.0f + e);
}

__device__ __forceinline__ unsigned f2bf(float x) {
    union { float f; unsigned u; } v; v.f = x;
    unsigned r = v.u + 0x7FFF + ((v.u >> 16) & 1);   // RNE
    return r >> 16;
}

__device__ __forceinline__ float bflo(unsigned u) {
    union { unsigned u; float f; } v; v.u = u << 16; return v.f;
}
__device__ __forceinline__ float bfhi(unsigned u) {
    union { unsigned u; float f; } v; v.u = u & 0xFFFF0000u; return v.f;
}

// K1: per (n, 32-t tile): MFMA projection -> tanh -> per-table softmax.
// Projection runs on matrix cores: A = [64 rows: K(0..31)|Q(32..63)][64 d] bf16
// (rows staged d-contiguous, NO transpose), B = planes^T [32 j][64 d] bf16.
// Outputs: pKB/pQB [n][lr][t], pKt [n][t][lr], VBT [n][d][t], Spart fp32.
__global__ __launch_bounds__(256) void k_probs(
    const float* __restrict__ Khf, const float* __restrict__ Qhf,
    const float* __restrict__ Vhf,
    const float* __restrict__ planesT, const float* __restrict__ protosT,
    unsigned short* __restrict__ pKB, unsigned short* __restrict__ pKt,
    unsigned short* __restrict__ pQB, unsigned short* __restrict__ VBT,
    float* __restrict__ Spart)
{
    __shared__ __align__(16) unsigned char smraw[39424];   // 38.5 KB
    short* Psh    = (short*)smraw;                 // [32][72] bf16 planes^T
    float* protos = (float*)(smraw + 4608);        // [4][16]
    short* Xsh    = (short*)(smraw + 4864);        // [64][72] bf16 (K rows 0..31, Q 32..63)
    float* xt     = (float*)(smraw + 14080);       // [64][33] tanh'd proj
    float* pbuf   = (float*)(smraw + 22528);       // [128][33]
    float* vb     = xt;                            // aliases xt (post-softmax)

    const int bx = blockIdx.x;
    const int n  = bx >> 4;               // 0..31
    const int tile = bx & 15;             // 0..15
    const int t0 = tile * 32;
    const int g  = n >> 3, h = n & 7;
    const int tid = threadIdx.x;
    const int wv = tid >> 6, lane = tid & 63, m16 = lane & 15, q = lane >> 4;

    // ---- stage planes^T (bf16 transpose, once) + protos + X rows ----
    {
        int d = tid >> 2, jb = (tid & 3) * 8;      // 64 d x 4 j-groups
        float4 a = *(const float4*)(planesT + d * 32 + jb);
        float4 b = *(const float4*)(planesT + d * 32 + jb + 4);
        float pv[8] = {a.x, a.y, a.z, a.w, b.x, b.y, b.z, b.w};
#pragma unroll
        for (int i = 0; i < 8; ++i)
            Psh[(jb + i) * 72 + d] = (short)f2bf(pv[i]);
    }
    if (tid < 64) protos[tid] = protosT[tid];
#pragma unroll
    for (int it = 0; it < 2; ++it) {
        int vid = it * 256 + tid;                  // 512 = 64 rows x 8 segs
        int row = vid >> 3, seg = vid & 7;
        const float* src = (row < 32 ? Khf : Qhf) +
            ((long)(g * T_LEN + t0 + (row & 31)) * H_HEADS + h) * DK + seg * 8;
        float4 a = *(const float4*)src;
        float4 b = *(const float4*)(src + 4);
        uint4 u;
        u.x = f2bf(a.x) | (f2bf(a.y) << 16);
        u.y = f2bf(a.z) | (f2bf(a.w) << 16);
        u.z = f2bf(b.x) | (f2bf(b.y) << 16);
        u.w = f2bf(b.z) | (f2bf(b.w) << 16);
        *(uint4*)(Xsh + row * 72 + seg * 8) = u;
    }
    __syncthreads();

    // ---- MFMA projection: [64 rows][32 j], K=64 (2 steps), 4 waves x 2 n-bands ----
    {
        f32x4 s[2];
        s[0] = s[1] = (f32x4){0.f, 0.f, 0.f, 0.f};
#pragma unroll
        for (int ks = 0; ks < 2; ++ks) {
            bf16x8 af = *(const bf16x8*)(Xsh + (wv * 16 + m16) * 72 + ks * 32 + q * 8);
#pragma unroll
            for (int nb = 0; nb < 2; ++nb) {
                bf16x8 bf = *(const bf16x8*)(Psh + (nb * 16 + m16) * 72 + ks * 32 + q * 8);
                s[nb] = __builtin_amdgcn_mfma_f32_16x16x32_bf16(af, bf, s[nb], 0, 0, 0);
            }
        }
        // C layout: row = q*4+p (within band), col = m16 -> xt[t2][j]
#pragma unroll
        for (int nb = 0; nb < 2; ++nb)
#pragma unroll
            for (int p = 0; p < 4; ++p)
                xt[(wv * 16 + q * 4 + p) * 33 + nb * 16 + m16] =
                    fast_tanh(s[nb][p]) * 0.125f;
    }
    __syncthreads();

    // ---- per-table softmax over 16 corners (|logit| <= 0.5) ----
    const int r = tid & 15, l = (tid >> 4) & 7, thi = tid >> 7;   // thi 0/1
    for (int side = 0; side < 2; ++side) {
        float p0 = protos[r], p1 = protos[16 + r], p2 = protos[32 + r], p3 = protos[48 + r];
#pragma unroll 4
        for (int w = 0; w < 16; ++w) {
            int tl = w * 2 + thi;                 // 0..31
            const float* x = xt + (side * 32 + tl) * 33 + l * 4;
            float logit = x[0] * p0 + x[1] * p1 + x[2] * p2 + x[3] * p3;
            float e = __expf(logit);
            float s = e;
            s += __shfl_xor(s, 1, 16);
            s += __shfl_xor(s, 2, 16);
            s += __shfl_xor(s, 4, 16);
            s += __shfl_xor(s, 8, 16);
            pbuf[(l * 16 + r) * 33 + tl] = e / s;
        }
        __syncthreads();
        // bf16 pack: pbuf [128 lr][32 t] -> (pKB|pQB)[n][lr][t0..t0+32)
        unsigned* dst = (unsigned*)(side ? pQB : pKB);
#pragma unroll
        for (int it = 0; it < 8; ++it) {
            int fid = it * 256 + tid;             // 2048 = 128 lr x 16 dwords
            int lr = fid >> 4, tp2 = fid & 15;
            unsigned u0 = f2bf(pbuf[lr * 33 + tp2 * 2]);
            unsigned u1 = f2bf(pbuf[lr * 33 + tp2 * 2 + 1]);
            dst[(size_t)(n * LR + lr) * 256 + tile * 16 + tp2] = u0 | (u1 << 16);
        }
        if (side == 0) {
            // transposed pack: pbuf [lr][t] -> pKt[n][t][lr]
            unsigned* dt = (unsigned*)pKt + (size_t)n * 32768 + t0 * 64;
#pragma unroll
            for (int it = 0; it < 8; ++it) {
                int fid = it * 256 + tid;         // 2048 = 32 t x 64 lr-pairs
                int t = fid >> 6, lrp = fid & 63;
                unsigned u0 = f2bf(pbuf[(2 * lrp) * 33 + t]);
                unsigned u1 = f2bf(pbuf[(2 * lrp + 1) * 33 + t]);
                dt[t * 64 + lrp] = u0 | (u1 << 16);
            }
            if (tid < 128) {                      // per-tile pK row sums (fp32)
                float s = 0.f;
                const float* row = pbuf + tid * 33;
#pragma unroll 8
                for (int t = 0; t < 32; ++t) s += row[t];
                Spart[((size_t)n * 16 + tile) * 128 + tid] = s;
            }
        }
        __syncthreads();
    }

    // ---- V pack: [t][d] fp32 -> VBT[n][d][t] bf16 via LDS transpose ----
#pragma unroll
    for (int it = 0; it < 2; ++it) {
        int fid = it * 256 + tid;                 // 512 = 32 t x 16 c4
        int t = fid >> 4, c4 = fid & 15;
        float4 v = *(const float4*)(Vhf + ((size_t)(g * T_LEN + t0 + t) * H_HEADS + h) * DK + c4 * 4);
        vb[(c4 * 4 + 0) * 33 + t] = v.x;
        vb[(c4 * 4 + 1) * 33 + t] = v.y;
        vb[(c4 * 4 + 2) * 33 + t] = v.z;
        vb[(c4 * 4 + 3) * 33 + t] = v.w;
    }
    __syncthreads();
    {
        unsigned* dstv = (unsigned*)VBT + (size_t)n * 16384;
#pragma unroll
        for (int it = 0; it < 4; ++it) {
            int fid = it * 256 + tid;             // 1024 = 64 d x 16 dwords
            int d = fid >> 4, tp2 = fid & 15;
            unsigned u0 = f2bf(vb[d * 33 + tp2 * 2]);
            unsigned u1 = f2bf(vb[d * 33 + tp2 * 2 + 1]);
            dstv[d * 256 + tile * 16 + tp2] = u0 | (u1 << 16);
        }
    }
}

// K2: MFMA causal attention, 1024 thr = 4 wave-groups x 4 m-band waves.
// A-prefix from Spart + bf16 in-tile scan; qw from bf16 pQB. Chunks c == wg
// (mod 4). Ksh staged directly from pKt[n][t][lr] via b128.
__global__ __launch_bounds__(1024) void k_attn(
    const unsigned short* __restrict__ pKB, const unsigned short* __restrict__ pKt,
    const unsigned short* __restrict__ pQB, const unsigned short* __restrict__ VBT,
    const float* __restrict__ Spart, float* __restrict__ out)
{
    __shared__ __align__(16) short sm[71680];      // 143,360 B
    const int n = blockIdx.x >> 3, rt = blockIdx.x & 7;
    const int g = n >> 3, h = n & 7;
    const int tid = threadIdx.x;
    const int wave = tid >> 6, wg = wave >> 2, w = wave & 3;
    const int lane = tid & 63, m16 = lane & 15, q = lane >> 4;
    const int gtid = tid & 255;

    short* Ksh = sm + wg * 8704;                   // [64][136] plain padded
    short* Vsh = sm + 34816 + wg * 4608;           // [64][72]
    short* Ssh = sm + 53248 + wg * 4608;           // [64][72]
    short* Qsh = sm;                               // aliases Ksh[0] pre-loop (XOR-swizzled)

    // ---- A-prefix + qw -> Qsh (bf16, swizzled) ----
    {
        const int s8 = lane & 7;
        const int lr = wave * 8 + (lane >> 3);     // 16 waves x 8 = 128
        float bsum = 0.f;
        for (int j = 0; j < 2 * rt; ++j)           // 32-t tile sums below rt*64
            bsum += Spart[((size_t)n * 16 + j) * 128 + lr];
        uint4 ku = *(const uint4*)(pKB + ((size_t)n * LR + lr) * 512 + rt * 64 + s8 * 8);
        unsigned kuu[4] = {ku.x, ku.y, ku.z, ku.w};
        float s[8];
        s[0] = bflo(kuu[0]);        s[1] = s[0] + bfhi(kuu[0]);
        s[2] = s[1] + bflo(kuu[1]); s[3] = s[2] + bfhi(kuu[1]);
        s[4] = s[3] + bflo(kuu[2]); s[5] = s[4] + bfhi(kuu[2]);
        s[6] = s[5] + bflo(kuu[3]); s[7] = s[6] + bfhi(kuu[3]);
        float tot = s[7];
#pragma unroll
        for (int off = 1; off < 8; off <<= 1) {    // segmented scan (width 8)
            float v = __shfl_up(tot, off, 8);
            if (s8 >= off) tot += v;
        }
        float base = bsum + tot - s[7];            // exclusive prefix before lane's span
        uint4 qu = *(const uint4*)(pQB + ((size_t)n * LR + lr) * 512 + rt * 64 + s8 * 8);
        unsigned quu[4] = {qu.x, qu.y, qu.z, qu.w};
        float qf[8] = {bflo(quu[0]), bfhi(quu[0]), bflo(quu[1]), bfhi(quu[1]),
                       bflo(quu[2]), bfhi(quu[2]), bflo(quu[3]), bfhi(quu[3])};
        const int qbase = ((wave ^ s8) << 3) + (lr & 7);   // lr>>3 == wave
#pragma unroll
        for (int i = 0; i < 8; ++i)
            Qsh[(s8 * 8 + i) * 136 + qbase] = (short)f2bf(qf[i] / (base + s[i] + 1e-6f));
    }
    __syncthreads();

    bf16x8 qa[4];
    {
        const int row = w * 16 + m16, rk = row >> 3;
#pragma unroll
        for (int st = 0; st < 4; ++st)
            qa[st] = *(const bf16x8*)(Qsh + row * 136 + (((st * 4 + q) ^ rk) << 3));
    }

    const unsigned short* kt = pKt + (size_t)n * 65536;   // [t][lr]
    const unsigned short* kv = VBT + (size_t)n * 32768;   // [d][t]
    uint4 pk[4], pv[2];
    auto pref = [&](int c) {
#pragma unroll
        for (int it = 0; it < 4; ++it) {           // 1024 uint4 = 64 rows x 16 segs
            int fid = it * 256 + gtid;
            pk[it] = *(const uint4*)(kt + (size_t)(c * 64 + (fid >> 4)) * 128 + (fid & 15) * 8);
        }
#pragma unroll
        for (int it = 0; it < 2; ++it) {
            int fid = it * 256 + gtid;
            pv[it] = *(const uint4*)(kv + (size_t)(fid >> 3) * 512 + c * 64 + (fid & 7) * 8);
        }
    };

    f32x4 o[4];
    o[0] = o[1] = o[2] = o[3] = (f32x4){0.f, 0.f, 0.f, 0.f};

    if (wg <= rt) pref(wg);
    const int rounds = (rt >> 2) + 1;
    for (int r0 = 0; r0 < rounds; ++r0) {
        const int c = r0 * 4 + wg;
        const bool act = (c <= rt);
        __syncthreads();                           // prior round reads done (also Q stage)
        if (act) {
#pragma unroll
            for (int it = 0; it < 4; ++it) {
                int fid = it * 256 + gtid;
                *(uint4*)(Ksh + (fid >> 4) * 136 + (fid & 15) * 8) = pk[it];
            }
            *(uint4*)(Vsh + (gtid >> 3) * 72 + (gtid & 7) * 8) = pv[0];
            *(uint4*)(Vsh + ((gtid + 256) >> 3) * 72 + (gtid & 7) * 8) = pv[1];
        }
        __syncthreads();
        if (c + 4 <= rt) pref(c + 4);
        if (act) {
            f32x4 s[4];
            s[0] = s[1] = s[2] = s[3] = (f32x4){0.f, 0.f, 0.f, 0.f};
#pragma unroll
            for (int st = 0; st < 4; ++st)
#pragma unroll
                for (int nb = 0; nb < 4; ++nb) {
                    bf16x8 b = *(const bf16x8*)(Ksh + (nb * 16 + m16) * 136 + st * 32 + q * 8);
                    s[nb] = __builtin_amdgcn_mfma_f32_16x16x32_bf16(qa[st], b, s[nb], 0, 0, 0);
                }
            if (c == rt) {                         // causal: keep j <= i
#pragma unroll
                for (int nb = 0; nb < 4; ++nb)
#pragma unroll
                    for (int p = 0; p < 4; ++p)
                        if (nb * 16 + m16 > w * 16 + q * 4 + p) s[nb][p] = 0.f;
            }
#pragma unroll
            for (int nb = 0; nb < 4; ++nb)
#pragma unroll
                for (int p = 0; p < 4; ++p) {
                    union { float f; unsigned u; } cv; cv.f = s[nb][p];
                    Ssh[(w * 16 + q * 4 + p) * 72 + nb * 16 + m16] =
                        (short)((cv.u + 0x8000u) >> 16);
                }
#pragma unroll
            for (int st = 0; st < 2; ++st) {
                bf16x8 a = *(const bf16x8*)(Ssh + (w * 16 + m16) * 72 + st * 32 + q * 8);
#pragma unroll
                for (int nb = 0; nb < 4; ++nb) {
                    bf16x8 b = *(const bf16x8*)(Vsh + (nb * 16 + m16) * 72 + st * 32 + q * 8);
                    o[nb] = __builtin_amdgcn_mfma_f32_16x16x32_bf16(a, b, o[nb], 0, 0, 0);
                }
            }
        }
    }

    // combine 4 wave-group partials via LDS (K/Q regions dead)
    __syncthreads();
    float* Obuf = (float*)sm;                      // 3 x [64][68] f32
    if (wg) {
        float* ob = Obuf + (wg - 1) * 4352;
#pragma unroll
        for (int nb = 0; nb < 4; ++nb)
#pragma unroll
            for (int p = 0; p < 4; ++p)
                ob[(w * 16 + q * 4 + p) * 68 + nb * 16 + m16] = o[nb][p];
    }
    __syncthreads();
    if (wg == 0) {
        float* dst = out + ((size_t)(g * T_LEN + rt * 64 + w * 16 + q * 4) * H_HEADS + h) * DK;
#pragma unroll
        for (int p = 0; p < 4; ++p)
#pragma unroll
            for (int nb = 0; nb < 4; ++nb) {
                int idx = (w * 16 + q * 4 + p) * 68 + nb * 16 + m16;
                dst[p * (H_HEADS * DK) + nb * 16 + m16] =
                    o[nb][p] + Obuf[idx] + Obuf[4352 + idx] + Obuf[8704 + idx];
            }
    }
}

extern "C" void kernel_launch(void* const* d_in, const int* in_sizes, int n_in,
                              void* d_out, int out_size, void* d_ws, size_t ws_size,
                              hipStream_t stream) {
    const float* Khf     = (const float*)d_in[0];
    const float* Vhf     = (const float*)d_in[1];
    const float* Qhf     = (const float*)d_in[2];
    const float* planesT = (const float*)d_in[3];
    const float* protosT = (const float*)d_in[4];
    float* outp = (float*)d_out;

    const size_t NE = (size_t)NTOT * LR * T_LEN;        // 2,097,152
    unsigned short* pKB = (unsigned short*)d_ws;        // bf16 [n][lr][t]
    unsigned short* pKt = pKB + NE;                     // bf16 [n][t][lr]
    unsigned short* pQB = pKt + NE;                     // bf16 [n][lr][t]
    unsigned short* VBT = pQB + NE;                     // bf16 [n][d][t]
    float* Spart = (float*)(VBT + (size_t)NTOT * DK * T_LEN);  // fp32 [n][16][128]

    k_probs<<<dim3(512), dim3(256), 0, stream>>>(
        Khf, Qhf, Vhf, planesT, protosT, pKB, pKt, pQB, VBT, Spart);
    k_attn<<<dim3(256), dim3(1024), 0, stream>>>(pKB, pKt, pQB, VBT, Spart, outp);
}